// Round 4
// baseline (518.425 us; speedup 1.0000x reference)
//
#include <hip/hip_runtime.h>

#define B_   32
#define NT_  1002
#define D_   128
#define H_   8
#define FF_  512
#define ROWS (B_ * NT_)          // 32064 = 501*64
#define NEGV (-1e9f)
#define NTP  1024                // padded rows per (b,head)

typedef __bf16 bf16;
typedef __bf16 bf16x8 __attribute__((ext_vector_type(8)));
typedef __bf16 bf16x4 __attribute__((ext_vector_type(4)));
typedef float  f32x4  __attribute__((ext_vector_type(4)));
typedef float  f32x16 __attribute__((ext_vector_type(16)));

// ---------------- weight prep: transpose + convert to bf16 [n][k] ----------------
#define SZ_QKV (2*384*128)
#define SZ_WO  (2*128*128)
#define SZ_W1  (2*512*128)
#define SZ_W2  (2*128*512)
#define SZ_PROJ (384*128)

__global__ __launch_bounds__(256) void prep_w(
    const float* __restrict__ qkv, const float* __restrict__ wo, const float* __restrict__ w1,
    const float* __restrict__ w2, const float* __restrict__ proj, bf16* __restrict__ out) {
  int i = blockIdx.x * 256 + threadIdx.x;
  int j = i;
  float v;
  if (j < SZ_QKV) {
    int l = j / 49152, r = j % 49152; int n = r >> 7, k = r & 127;
    v = qkv[((size_t)l * 128 + k) * 384 + n];
  } else {
    j -= SZ_QKV;
    if (j < SZ_WO) {
      int l = j >> 14, r = j & 16383; int n = r >> 7, k = r & 127;
      v = wo[((size_t)l * 128 + k) * 128 + n];
    } else {
      j -= SZ_WO;
      if (j < SZ_W1) {
        int l = j >> 16, r = j & 65535; int n = r >> 7, k = r & 127;
        v = w1[((size_t)l * 128 + k) * 512 + n];
      } else {
        j -= SZ_W1;
        if (j < SZ_W2) {
          int l = j >> 16, r = j & 65535; int n = r >> 9, k = r & 511;
          v = w2[((size_t)l * 512 + k) * 128 + n];
        } else {
          j -= SZ_W2;
          int n = j >> 7, k = j & 127;
          v = proj[(size_t)k * 384 + n];
        }
      }
    }
  }
  out[i] = (bf16)v;
}

// ---------------- init embeddings (bf16 only) ----------------
__global__ __launch_bounds__(256) void init_kernel(
    const float* __restrict__ depot, const float* __restrict__ loc, const float* __restrict__ demand,
    const float* __restrict__ Wn, const float* __restrict__ bn_, const float* __restrict__ Wd,
    const float* __restrict__ bd, bf16* __restrict__ hb) {
  int idx = blockIdx.x * 256 + threadIdx.x;
  if (idx >= ROWS * D_) return;
  int c = idx & 127;
  int row = idx >> 7;
  int b = row / NT_;
  int n = row - b * NT_;
  float v;
  if (n < 2) {
    const float* dp = depot + (b * 2 + n) * 2;
    v = dp[0] * Wd[c] + dp[1] * Wd[D_ + c] + bd[c];
  } else {
    int i = n - 2;
    const float* lp = loc + ((size_t)b * 1000 + i) * 2;
    v = lp[0] * Wn[c] + lp[1] * Wn[D_ + c] + demand[b * 1000 + i] * Wn[2 * D_ + c] + bn_[c];
  }
  hb[idx] = (bf16)v;
}

// ---------------- MFMA GEMM: C[M=ROWS, N_] = A[M,K_](bf16) @ W(bf16 [N][K]) ----------------
template<int N_, int K_, bool OUTBF, bool BIAS, bool RELU, bool RES>
__global__ __launch_bounds__(256) void mgemm(
    const bf16* __restrict__ A, const bf16* __restrict__ Wt,
    const float* __restrict__ bias, const bf16* __restrict__ R, void* __restrict__ Cout) {
  __shared__ bf16 As[64][40];
  __shared__ bf16 Bs[64][40];
  int tid = threadIdx.x;
  int w = tid >> 6, l = tid & 63;
  int bm = blockIdx.y * 64, bn = blockIdx.x * 64;
  int wr = (w >> 1) * 32, wc = (w & 1) * 32;
  f32x4 acc[2][2] = {};
  int sr = tid >> 2, ss = (tid & 3) * 8;
  for (int k0 = 0; k0 < K_; k0 += 32) {
    __syncthreads();
    *(bf16x8*)&As[sr][ss] = *(const bf16x8*)&A[(size_t)(bm + sr) * K_ + k0 + ss];
    *(bf16x8*)&Bs[sr][ss] = *(const bf16x8*)&Wt[(size_t)(bn + sr) * K_ + k0 + ss];
    __syncthreads();
    bf16x8 af[2], bfr[2];
#pragma unroll
    for (int mi = 0; mi < 2; ++mi) af[mi] = *(const bf16x8*)&As[wr + mi * 16 + (l & 15)][(l >> 4) * 8];
#pragma unroll
    for (int ni = 0; ni < 2; ++ni) bfr[ni] = *(const bf16x8*)&Bs[wc + ni * 16 + (l & 15)][(l >> 4) * 8];
#pragma unroll
    for (int mi = 0; mi < 2; ++mi)
#pragma unroll
      for (int ni = 0; ni < 2; ++ni)
        acc[mi][ni] = __builtin_amdgcn_mfma_f32_16x16x32_bf16(af[mi], bfr[ni], acc[mi][ni], 0, 0, 0);
  }
#pragma unroll
  for (int mi = 0; mi < 2; ++mi)
#pragma unroll
    for (int ni = 0; ni < 2; ++ni)
#pragma unroll
      for (int r = 0; r < 4; ++r) {
        int row = bm + wr + mi * 16 + (l >> 4) * 4 + r;
        int col = bn + wc + ni * 16 + (l & 15);
        float v = acc[mi][ni][r];
        if (BIAS) v += bias[col];
        if (RELU) v = fmaxf(v, 0.f);
        if (RES)  v += (float)R[(size_t)row * N_ + col];
        if (OUTBF) ((bf16*)Cout)[(size_t)row * N_ + col] = (bf16)v;
        else       ((float*)Cout)[(size_t)row * N_ + col] = v;
      }
}

// ---------------- QKV GEMM with head-major scatter epilogue ----------------
// writes Qh/Kh/Vh as [b*8+h][NTP][16] bf16
__global__ __launch_bounds__(256) void mgemm_qkv(
    const bf16* __restrict__ A, const bf16* __restrict__ Wt,
    bf16* __restrict__ Qh, bf16* __restrict__ Kh, bf16* __restrict__ Vh) {
  __shared__ bf16 As[64][40];
  __shared__ bf16 Bs[64][40];
  int tid = threadIdx.x;
  int w = tid >> 6, l = tid & 63;
  int bm = blockIdx.y * 64, bn = blockIdx.x * 64;
  int wr = (w >> 1) * 32, wc = (w & 1) * 32;
  f32x4 acc[2][2] = {};
  int sr = tid >> 2, ss = (tid & 3) * 8;
  for (int k0 = 0; k0 < 128; k0 += 32) {
    __syncthreads();
    *(bf16x8*)&As[sr][ss] = *(const bf16x8*)&A[(size_t)(bm + sr) * 128 + k0 + ss];
    *(bf16x8*)&Bs[sr][ss] = *(const bf16x8*)&Wt[(size_t)(bn + sr) * 128 + k0 + ss];
    __syncthreads();
    bf16x8 af[2], bfr[2];
#pragma unroll
    for (int mi = 0; mi < 2; ++mi) af[mi] = *(const bf16x8*)&As[wr + mi * 16 + (l & 15)][(l >> 4) * 8];
#pragma unroll
    for (int ni = 0; ni < 2; ++ni) bfr[ni] = *(const bf16x8*)&Bs[wc + ni * 16 + (l & 15)][(l >> 4) * 8];
#pragma unroll
    for (int mi = 0; mi < 2; ++mi)
#pragma unroll
      for (int ni = 0; ni < 2; ++ni)
        acc[mi][ni] = __builtin_amdgcn_mfma_f32_16x16x32_bf16(af[mi], bfr[ni], acc[mi][ni], 0, 0, 0);
  }
#pragma unroll
  for (int ni = 0; ni < 2; ++ni) {
    int col = bn + wc + ni * 16 + (l & 15);
    bf16* dst = (col < 128) ? Qh : (col < 256) ? Kh : Vh;
    int hd = (col >> 4) & 7, c16 = col & 15;
#pragma unroll
    for (int mi = 0; mi < 2; ++mi)
#pragma unroll
      for (int r = 0; r < 4; ++r) {
        int row = bm + wr + mi * 16 + (l >> 4) * 4 + r;
        int b = row / NT_;
        int n = row - b * NT_;
        dst[(((size_t)b * 8 + hd) * NTP + n) * 16 + c16] = (bf16)acc[mi][ni][r];
      }
  }
}

// ---------------- MFMA flash attention (head-major inputs) ----------------
__global__ __launch_bounds__(256) void mattn(
    const bf16* __restrict__ Qh, const bf16* __restrict__ Kh,
    const bf16* __restrict__ Vh, bf16* __restrict__ ab) {
  __shared__ bf16 Ks[64][24];
  __shared__ bf16 Vt[16][72];
  __shared__ bf16 Ps[4][32][72];
  __shared__ float corrW[4][32];
  __shared__ float invW[4][32];
  int tid = threadIdx.x;
  int w = tid >> 6, l = tid & 63;
  int bh = blockIdx.x;
  int b = bh >> 3, hd = bh & 7;
  const bf16* Qp = Qh + (size_t)bh * NTP * 16;
  const bf16* Kp = Kh + (size_t)bh * NTP * 16;
  const bf16* Vp = Vh + (size_t)bh * NTP * 16;
  int qbase = blockIdx.y * 128 + w * 32;
  int qrow = qbase + (l & 31); if (qrow >= NT_) qrow = NT_ - 1;
  bf16x8 qf = *(const bf16x8*)&Qp[qrow * 16 + (l >> 5) * 8];

  const float SC = 0.25f * 1.44269504088896f;  // (1/sqrt(16)) * log2(e)
  float m = 0.f, lsum = 0.f;
  f32x4 oacc[2] = {};
  const f32x16 zz = {0,0,0,0,0,0,0,0,0,0,0,0,0,0,0,0};

  int sr = (tid & 127) >> 1, sh = (tid & 1) * 8;
  for (int t = 0; t < 16; ++t) {
    int kb = t * 64;
    int krow = kb + sr; if (krow >= NT_) krow = NT_ - 1;
    __syncthreads();
    if (tid < 128) {
      *(bf16x8*)&Ks[sr][sh] = *(const bf16x8*)&Kp[krow * 16 + sh];
    } else {
      bf16x8 v8 = *(const bf16x8*)&Vp[krow * 16 + sh];
#pragma unroll
      for (int j = 0; j < 8; ++j) Vt[sh + j][sr] = v8[j];
    }
    __syncthreads();

    // S^T = K @ Q^T (raw scores; scale folded into exp2)
    f32x16 sv[2];
#pragma unroll
    for (int c = 0; c < 2; ++c) {
      bf16x8 kf = *(const bf16x8*)&Ks[c * 32 + (l & 31)][(l >> 5) * 8];
      sv[c] = __builtin_amdgcn_mfma_f32_32x32x16_bf16(kf, qf, zz, 0, 0, 0);
    }
    if (kb + 64 > NT_) {  // tail mask
#pragma unroll
      for (int c = 0; c < 2; ++c)
#pragma unroll
        for (int r = 0; r < 16; ++r) {
          int key = kb + c * 32 + (r & 3) + 8 * (r >> 2) + 4 * (l >> 5);
          if (key >= NT_) sv[c][r] = -1e30f;
        }
    }
    // tile max (per q row; lane l pairs with l^32)
    float tm = -1e30f;
#pragma unroll
    for (int c = 0; c < 2; ++c)
#pragma unroll
      for (int r = 0; r < 16; ++r) tm = fmaxf(tm, sv[c][r]);
    tm = fmaxf(tm, __shfl_xor(tm, 32));
    // defer-max: rescale only if max grew past threshold (raw-score THR=8 -> P <= e^2)
    if (!__all(tm <= m + 8.f)) {
      float nm = fmaxf(m, tm);
      float corr = exp2f((m - nm) * SC);
      m = nm;
      if (l < 32) corrW[w][l] = corr;
      lsum *= corr;
      f32x4 cv[2];
#pragma unroll
      for (int g = 0; g < 2; ++g) {
        cv[g] = *(const f32x4*)&corrW[w][g * 16 + (l >> 4) * 4];
#pragma unroll
        for (int r = 0; r < 4; ++r) oacc[g][r] *= cv[g][r];
      }
    }
    float mc = m * SC;
    float ls = 0.f;
#pragma unroll
    for (int c = 0; c < 2; ++c)
#pragma unroll
      for (int r = 0; r < 16; ++r) {
        float e = exp2f(__builtin_fmaf(sv[c][r], SC, -mc));
        sv[c][r] = e; ls += e;
      }
    lsum += ls;
    // pack P -> per-wave LDS tile [q 32][key 64]
#pragma unroll
    for (int c = 0; c < 2; ++c)
#pragma unroll
      for (int g2 = 0; g2 < 4; ++g2) {
        bf16x4 pk;
#pragma unroll
        for (int i = 0; i < 4; ++i) pk[i] = (bf16)sv[c][g2 * 4 + i];
        *(bf16x4*)&Ps[w][l & 31][c * 32 + 8 * g2 + 4 * (l >> 5)] = pk;
      }
    // PV: O += P @ V
#pragma unroll
    for (int kh = 0; kh < 2; ++kh) {
      bf16x8 vf = *(const bf16x8*)&Vt[l & 15][kh * 32 + (l >> 4) * 8];
#pragma unroll
      for (int g = 0; g < 2; ++g) {
        bf16x8 pf = *(const bf16x8*)&Ps[w][g * 16 + (l & 15)][kh * 32 + (l >> 4) * 8];
        oacc[g] = __builtin_amdgcn_mfma_f32_16x16x32_bf16(pf, vf, oacc[g], 0, 0, 0);
      }
    }
  }
  lsum = lsum + __shfl_xor(lsum, 32);
  if (l < 32) invW[w][l] = 1.f / lsum;
#pragma unroll
  for (int g = 0; g < 2; ++g) {
    f32x4 iv = *(const f32x4*)&invW[w][g * 16 + (l >> 4) * 4];
#pragma unroll
    for (int r = 0; r < 4; ++r) {
      int qq = qbase + g * 16 + (l >> 4) * 4 + r;
      if (qq < NT_) ab[((size_t)b * NT_ + qq) * 128 + hd * 16 + (l & 15)] = (bf16)(oacc[g][r] * iv[r]);
    }
  }
}

// ---------------- BN stats (two-stage, deterministic) ----------------
__global__ __launch_bounds__(256) void stats_partial(const float* __restrict__ X,
                                                     float* __restrict__ psum, float* __restrict__ psq) {
  int c = threadIdx.x & 127;
  int half = threadIdx.x >> 7;
  float s = 0.f, q = 0.f;
  for (int rp = blockIdx.x; rp < ROWS / 2; rp += 256) {
    int row = rp * 2 + half;
    float v = X[(size_t)row * D_ + c];
    s += v; q += v * v;
  }
  __shared__ float ss[256], sq2[256];
  ss[threadIdx.x] = s; sq2[threadIdx.x] = q;
  __syncthreads();
  if (threadIdx.x < 128) {
    psum[blockIdx.x * 128 + threadIdx.x] = ss[threadIdx.x] + ss[threadIdx.x + 128];
    psq[blockIdx.x * 128 + threadIdx.x]  = sq2[threadIdx.x] + sq2[threadIdx.x + 128];
  }
}

__global__ void stats_final(const float* __restrict__ psum, const float* __restrict__ psq,
                            float* __restrict__ mi) {
  int c = threadIdx.x;  // 128
  float s = 0.f, q = 0.f;
  for (int p = 0; p < 256; ++p) { s += psum[p * 128 + c]; q += psq[p * 128 + c]; }
  float mean = s * (1.f / (float)ROWS);
  float var = q * (1.f / (float)ROWS) - mean * mean;
  mi[c] = mean;
  mi[128 + c] = rsqrtf(var + 1e-5f);
}

__global__ __launch_bounds__(256) void bn_apply(const float* __restrict__ X, const float* __restrict__ mi,
                                                const float* __restrict__ sc, const float* __restrict__ bi,
                                                bf16* __restrict__ Yb) {
  int idx = blockIdx.x * 256 + threadIdx.x;
  if (idx < ROWS * D_) {
    int c = idx & 127;
    Yb[idx] = (bf16)(sc[c] * (X[idx] - mi[c]) * mi[128 + c] + bi[c]);
  }
}

// ---------------- decoder ----------------
__global__ void ge_partial(const bf16* __restrict__ hb, float* __restrict__ part) {
  int b = blockIdx.x, ch = blockIdx.y, d = threadIdx.x;  // 32 x 8 blocks, 128 thr
  int n0 = ch * 126, n1 = n0 + 126; if (n1 > NT_) n1 = NT_;
  float s = 0.f;
  for (int n = n0; n < n1; ++n) s += (float)hb[((size_t)b * NT_ + n) * D_ + d];
  part[(b * 8 + ch) * D_ + d] = s;
}

__global__ void query_kernel(const float* __restrict__ part, const bf16* __restrict__ hb,
                             const float* __restrict__ Wf, const float* __restrict__ Ws,
                             float* __restrict__ qry) {
  __shared__ float sge[128], sh0[128];
  int b = blockIdx.x, d = threadIdx.x;  // 32 x 128
  float s = 0.f;
#pragma unroll
  for (int ch = 0; ch < 8; ++ch) s += part[(b * 8 + ch) * D_ + d];
  sge[d] = s * (1.f / (float)NT_);
  sh0[d] = (float)hb[(size_t)b * NT_ * D_ + d];
  __syncthreads();
  float q = 0.f;
  for (int k = 0; k < 128; ++k) q += sge[k] * Wf[k * D_ + d] + sh0[k] * Ws[k * D_ + d];
  qry[b * D_ + d] = q;
}

__global__ __launch_bounds__(256) void glimpse_kernel(
    const bf16* __restrict__ proj, const float* __restrict__ qry,
    const int* __restrict__ mask, float* __restrict__ glimpse) {
  int bid = blockIdx.x; int b = bid >> 3, hd = bid & 7;
  int tid = threadIdx.x;
  __shared__ float sq[16];
  __shared__ float sex[NT_];
  __shared__ float rmax[4];
  __shared__ float wacc[4][17];
  if (tid < 16) sq[tid] = qry[b * 128 + hd * 16 + tid];
  __syncthreads();
  const bf16* P = proj + (size_t)b * NT_ * 384;
  const int* Mk = mask + b * NT_;
  float lmax = -1e30f;
#pragma unroll
  for (int it = 0; it < 4; ++it) {
    int n = tid + it * 256;
    if (n < NT_) {
      float c = NEGV;
      if (!Mk[n]) {
        const bf16* kp = &P[(size_t)n * 384 + hd * 16];
        bf16x8 k0 = *(const bf16x8*)kp, k1 = *(const bf16x8*)(kp + 8);
        float d = 0.f;
#pragma unroll
        for (int i = 0; i < 8; ++i) d += sq[i] * (float)k0[i] + sq[8 + i] * (float)k1[i];
        c = d * 0.25f;
      }
      sex[n] = c;
      lmax = fmaxf(lmax, c);
    }
  }
#pragma unroll
  for (int o = 32; o > 0; o >>= 1) lmax = fmaxf(lmax, __shfl_xor(lmax, o));
  if ((tid & 63) == 0) rmax[tid >> 6] = lmax;
  __syncthreads();
  float mx = fmaxf(fmaxf(rmax[0], rmax[1]), fmaxf(rmax[2], rmax[3]));
  float acc[16];
#pragma unroll
  for (int i = 0; i < 16; ++i) acc[i] = 0.f;
  float lsum = 0.f;
#pragma unroll
  for (int it = 0; it < 4; ++it) {
    int n = tid + it * 256;
    if (n < NT_) {
      float e = __expf(sex[n] - mx);
      lsum += e;
      const bf16* vp = &P[(size_t)n * 384 + 128 + hd * 16];
      bf16x8 v0 = *(const bf16x8*)vp, v1 = *(const bf16x8*)(vp + 8);
#pragma unroll
      for (int i = 0; i < 8; ++i) { acc[i] += e * (float)v0[i]; acc[8 + i] += e * (float)v1[i]; }
    }
  }
#pragma unroll
  for (int o = 32; o > 0; o >>= 1) {
    lsum += __shfl_xor(lsum, o);
#pragma unroll
    for (int i = 0; i < 16; ++i) acc[i] += __shfl_xor(acc[i], o);
  }
  if ((tid & 63) == 0) {
    wacc[tid >> 6][16] = lsum;
#pragma unroll
    for (int i = 0; i < 16; ++i) wacc[tid >> 6][i] = acc[i];
  }
  __syncthreads();
  if (tid < 16) {
    float a = wacc[0][tid] + wacc[1][tid] + wacc[2][tid] + wacc[3][tid];
    float L = wacc[0][16] + wacc[1][16] + wacc[2][16] + wacc[3][16];
    glimpse[b * 128 + hd * 16 + tid] = a / L;
  }
}

__global__ void g2_kernel(const float* __restrict__ glimpse, const float* __restrict__ Wout,
                          float* __restrict__ g2) {
  __shared__ float sg[128];
  int b = blockIdx.x, d = threadIdx.x;  // 32 x 128
  sg[d] = glimpse[b * 128 + d];
  __syncthreads();
  float s = 0.f;
  for (int k = 0; k < 128; ++k) s += sg[k] * Wout[k * 128 + d];
  g2[b * 128 + d] = s;
}

__global__ __launch_bounds__(256) void logits_kernel(
    const bf16* __restrict__ proj, const float* __restrict__ g2,
    const int* __restrict__ mask, float* __restrict__ logits) {
  int b = blockIdx.y;
  int n = blockIdx.x * 256 + threadIdx.x;
  __shared__ float sg[128];
  if (threadIdx.x < 128) sg[threadIdx.x] = g2[b * 128 + threadIdx.x];
  __syncthreads();
  if (n >= NT_) return;
  const bf16* kp = &proj[((size_t)b * NT_ + n) * 384 + 256];
  float d = 0.f;
#pragma unroll
  for (int j = 0; j < 16; ++j) {
    bf16x8 v = *(const bf16x8*)&kp[j * 8];
#pragma unroll
    for (int i = 0; i < 8; ++i) d += sg[j * 8 + i] * (float)v[i];
  }
  d = 10.f * tanhf(d * 0.088388347648318447f);
  logits[b * NT_ + n] = mask[b * NT_ + n] ? NEGV : d;
}

__global__ __launch_bounds__(256) void lsm_kernel(const float* __restrict__ logits, float* __restrict__ out) {
  int b = blockIdx.x, tid = threadIdx.x;
  __shared__ float red[256];
  float mx = -1e30f;
  for (int n = tid; n < NT_; n += 256) mx = fmaxf(mx, logits[b * NT_ + n]);
  red[tid] = mx; __syncthreads();
  for (int s = 128; s > 0; s >>= 1) { if (tid < s) red[tid] = fmaxf(red[tid], red[tid + s]); __syncthreads(); }
  mx = red[0]; __syncthreads();
  float sm = 0.f;
  for (int n = tid; n < NT_; n += 256) sm += __expf(logits[b * NT_ + n] - mx);
  red[tid] = sm; __syncthreads();
  for (int s = 128; s > 0; s >>= 1) { if (tid < s) red[tid] += red[tid + s]; __syncthreads(); }
  float lse = mx + logf(red[0]);
  for (int n = tid; n < NT_; n += 256) out[(size_t)b * NT_ + n] = logits[b * NT_ + n] - lse;
}

// ---------------- launcher ----------------
extern "C" void kernel_launch(void* const* d_in, const int* in_sizes, int n_in,
                              void* d_out, int out_size, void* d_ws, size_t ws_size,
                              hipStream_t stream) {
  const float* depot        = (const float*)d_in[0];
  const float* loc          = (const float*)d_in[1];
  const float* demand       = (const float*)d_in[2];
  const int*   mask         = (const int*)d_in[3];
  const float* W_init_node  = (const float*)d_in[4];
  const float* b_init_node  = (const float*)d_in[5];
  const float* W_init_depot = (const float*)d_in[6];
  const float* b_init_depot = (const float*)d_in[7];
  const float* enc_Wqkv     = (const float*)d_in[8];
  const float* enc_Wo       = (const float*)d_in[9];
  const float* enc_W1       = (const float*)d_in[10];
  const float* enc_b1       = (const float*)d_in[11];
  const float* enc_W2       = (const float*)d_in[12];
  const float* enc_b2       = (const float*)d_in[13];
  const float* bn1_s        = (const float*)d_in[14];
  const float* bn1_b        = (const float*)d_in[15];
  const float* bn2_s        = (const float*)d_in[16];
  const float* bn2_b        = (const float*)d_in[17];
  const float* W_proj       = (const float*)d_in[18];
  const float* W_fixed      = (const float*)d_in[19];
  const float* W_step       = (const float*)d_in[20];
  const float* W_out        = (const float*)d_in[21];
  float* out = (float*)d_out;

  char* base = (char*)d_ws;
  bf16*  hb    = (bf16*)(base);                        //  8,208,384 B
  bf16*  ab    = (bf16*)(base + 8208384);              //  8,208,384 B
  char*  qreg  = base + 16416768;                      // 25,165,824 B region (Qh/Kh/Vh | xb | projb)
  bf16*  Qh    = (bf16*)qreg;                          // 256*1024*16 bf16 = 8,388,608 B
  bf16*  Kh    = (bf16*)(qreg + 8388608);
  bf16*  Vh    = (bf16*)(qreg + 16777216);
  float* xb    = (float*)qreg;                         // ROWS*128 f32 = 16,416,768 B (alias, disjoint lifetime)
  bf16*  projb = (bf16*)qreg;                          // ROWS*384 bf16 (decoder phase)
  bf16*  ff1b  = (bf16*)(base + 41582592);             // 32,833,536 B
  bf16*  wb    = (bf16*)(base + 74416128);             // 884,736 B
  float* psum  = (float*)(base + 75300864);            // 131,072 B
  float* psq   = (float*)(base + 75431936);            // 131,072 B
  float* mi    = (float*)(base + 75563008);            // 1,024 B
  float* qry   = (float*)(base + 75564032);            // 16,384 B
  float* glim  = (float*)(base + 75580416);            // 16,384 B
  float* g2    = (float*)(base + 75596800);            // 16,384 B
  float* gep   = psum;                                 // decoder reuse
  float* logit = psq;                                  // decoder reuse (128,256 B fits)

  bf16* wt_qkv  = wb;
  bf16* wt_wo   = wb + SZ_QKV;
  bf16* wt_w1   = wb + SZ_QKV + SZ_WO;
  bf16* wt_w2   = wb + SZ_QKV + SZ_WO + SZ_W1;
  bf16* wt_proj = wb + SZ_QKV + SZ_WO + SZ_W1 + SZ_W2;

  prep_w<<<1728, 256, 0, stream>>>(enc_Wqkv, enc_Wo, enc_W1, enc_W2, W_proj, wb);
  init_kernel<<<(ROWS * D_ + 255) / 256, 256, 0, stream>>>(
      depot, loc, demand, W_init_node, b_init_node, W_init_depot, b_init_depot, hb);

  for (int l = 0; l < 2; ++l) {
    mgemm_qkv<<<dim3(6, 501), 256, 0, stream>>>(
        hb, wt_qkv + (size_t)l * 384 * 128, Qh, Kh, Vh);
    mattn<<<dim3(256, 8), 256, 0, stream>>>(Qh, Kh, Vh, ab);
    mgemm<128, 128, false, false, false, true><<<dim3(2, 501), 256, 0, stream>>>(
        ab, wt_wo + (size_t)l * 128 * 128, nullptr, hb, xb);
    stats_partial<<<256, 256, 0, stream>>>(xb, psum, psq);
    stats_final<<<1, 128, 0, stream>>>(psum, psq, mi);
    bn_apply<<<(ROWS * D_ + 255) / 256, 256, 0, stream>>>(xb, mi, bn1_s + l * D_, bn1_b + l * D_, hb);
    mgemm<512, 128, true, true, true, false><<<dim3(8, 501), 256, 0, stream>>>(
        hb, wt_w1 + (size_t)l * 512 * 128, enc_b1 + (size_t)l * FF_, nullptr, ff1b);
    mgemm<128, 512, false, true, false, true><<<dim3(2, 501), 256, 0, stream>>>(
        ff1b, wt_w2 + (size_t)l * 128 * 512, enc_b2 + (size_t)l * D_, hb, xb);
    stats_partial<<<256, 256, 0, stream>>>(xb, psum, psq);
    stats_final<<<1, 128, 0, stream>>>(psum, psq, mi);
    bn_apply<<<(ROWS * D_ + 255) / 256, 256, 0, stream>>>(xb, mi, bn2_s + l * D_, bn2_b + l * D_, hb);
  }

  // decoder
  mgemm<384, 128, true, false, false, false><<<dim3(6, 501), 256, 0, stream>>>(
      hb, wt_proj, nullptr, nullptr, projb);
  ge_partial<<<dim3(32, 8), 128, 0, stream>>>(hb, gep);
  query_kernel<<<32, 128, 0, stream>>>(gep, hb, W_fixed, W_step, qry);
  glimpse_kernel<<<256, 256, 0, stream>>>(projb, qry, mask, glim);
  g2_kernel<<<32, 128, 0, stream>>>(glim, W_out, g2);
  logits_kernel<<<dim3(4, 32), 256, 0, stream>>>(projb, g2, mask, logit);
  lsm_kernel<<<32, 256, 0, stream>>>(logit, out);
}